// Round 3
// baseline (181.113 us; speedup 1.0000x reference)
//
#include <hip/hip_runtime.h>
#include <hip/hip_bf16.h>
#include <math.h>

#define HW_TOT (480*640)   // 307200 pixels per image
#define NBATCH 4
#define NB 128             // bins
#define NGAP (NB+1)        // gaps between sorted bins (incl. below/above)
#define EPSV 1e-10f
#define INF_BITS 0x7F800000u

// Workspace layout in d_ws (re-poisoned to 0xAA before every launch; k_setup
// re-initializes everything each call).
struct Ws {
  double acc[4];                 // cnt, sum_d, sum_d2, sum_l2 (global over batches)
  double t2b[NBATCH];            // per-batch sum over valid pixels of min dist^2 to bins
  unsigned tmax_bits[NBATCH];    // masked max of target per batch (float bits; all vals >= 0)
  int maskmode;                  // 0 = byte mask (bool), 1 = word mask (int32/f32 nonzero)
  int pad_;
  float bn[NBATCH][NB];          // sorted normalized bin edges
  unsigned gmin[NBATCH][NGAP];   // per-gap min of normalized target (float bits)
  unsigned gmax[NBATCH][NGAP];   // per-gap max
};

// ---------------- setup: mask-mode detect, init, bmax, normalize + bitonic sort bins
__global__ __launch_bounds__(512) void k_setup(const float* __restrict__ bins,
                                               const void* __restrict__ mask,
                                               Ws* __restrict__ ws) {
  __shared__ float sb[NBATCH][NB];
  __shared__ float smax[NBATCH][64];
  const int tid = threadIdx.x;
  const int b = tid >> 7, j = tid & 127;

  if (tid == 0) {
    // Detect mask element width by counting NONZERO bytes in the first 1024:
    // byte-bool (0x01 or 0xFF, ~95% true) -> ~972 nonzero; int32 -> ~243
    // (low byte only); float32 1.0f -> ~486 (two nonzero bytes/elem).
    // Threshold 768 separates byte-bool from the 4-byte encodings (>10 sigma).
    const unsigned char* m8 = (const unsigned char*)mask;
    int cnt = 0;
    for (int i = 0; i < 1024; ++i) cnt += (m8[i] != 0);
    ws->maskmode = (cnt >= 768) ? 0 : 1;
  }
  if (tid < 4) ws->acc[tid] = 0.0;
  if (tid < NBATCH) { ws->t2b[tid] = 0.0; ws->tmax_bits[tid] = 0u; }
  for (int i = tid; i < NBATCH * NGAP; i += blockDim.x) {
    (&ws->gmin[0][0])[i] = INF_BITS;  // +inf
    (&ws->gmax[0][0])[i] = 0u;        // 0.0f (all normalized targets >= 0)
  }

  const float e = bins[b * NB + j];
  sb[b][j] = e;
  __syncthreads();
  if (j < 64) smax[b][j] = fmaxf(sb[b][j], sb[b][j + 64]);
  __syncthreads();
  for (int s = 32; s > 0; s >>= 1) {
    if (j < s) smax[b][j] = fmaxf(smax[b][j], smax[b][j + s]);
    __syncthreads();
  }
  const float bmax = smax[b][0];
  __syncthreads();
  sb[b][j] = e / bmax;               // faithful f32 division like the reference
  __syncthreads();
  // bitonic sort ascending, n=128, per batch (all batches in lockstep)
  for (int k = 2; k <= NB; k <<= 1) {
    for (int jj = k >> 1; jj > 0; jj >>= 1) {
      int ixj = j ^ jj;
      if (ixj > j) {
        float a = sb[b][j], c = sb[b][ixj];
        bool up = ((j & k) == 0);
        if (up ? (a > c) : (a < c)) { sb[b][j] = c; sb[b][ixj] = a; }
      }
      __syncthreads();
    }
  }
  ws->bn[b][j] = sb[b][j];
}

// ---------------- pass 1: masked tmax per batch + SILog/L2 partial sums
__global__ __launch_bounds__(256) void k_stats(const float* __restrict__ pred,
                                               const float* __restrict__ targ,
                                               const void* __restrict__ mask,
                                               Ws* __restrict__ ws) {
  const int b = blockIdx.y;
  const int base = b * HW_TOT;
  const int i = (blockIdx.x * 256 + threadIdx.x) * 4;  // exact cover: 300*256*4 == HW_TOT
  const int mode = ws->maskmode;

  const float4 t4 = *(const float4*)(targ + base + i);
  const float4 p4 = *(const float4*)(pred + base + i);
  float t[4] = {t4.x, t4.y, t4.z, t4.w};
  float p[4] = {p4.x, p4.y, p4.z, p4.w};
  float m[4];
  if (mode == 0) {
    unsigned mw = *(const unsigned*)((const unsigned char*)mask + base + i);
    m[0] = (mw & 0xFFu)        ? 1.f : 0.f;
    m[1] = ((mw >> 8) & 0xFFu) ? 1.f : 0.f;
    m[2] = ((mw >> 16) & 0xFFu)? 1.f : 0.f;
    m[3] = (mw >> 24)          ? 1.f : 0.f;
  } else {
    int4 mi = *(const int4*)((const int*)mask + base + i);
    m[0] = mi.x ? 1.f : 0.f; m[1] = mi.y ? 1.f : 0.f;
    m[2] = mi.z ? 1.f : 0.f; m[3] = mi.w ? 1.f : 0.f;
  }

  float cnt = 0.f, sd = 0.f, sd2 = 0.f, sl2 = 0.f, tm = 0.f;
#pragma unroll
  for (int k = 0; k < 4; ++k) {
    float d = logf(p[k] + EPSV) - logf(t[k] + EPSV);
    cnt += m[k];
    sd  += m[k] * d;
    sd2 += m[k] * d * d;
    float e = p[k] - t[k];
    sl2 += m[k] * e * e;
    if (m[k] != 0.f) tm = fmaxf(tm, t[k]);
  }
#pragma unroll
  for (int off = 32; off > 0; off >>= 1) {
    cnt += __shfl_down(cnt, off);
    sd  += __shfl_down(sd,  off);
    sd2 += __shfl_down(sd2, off);
    sl2 += __shfl_down(sl2, off);
    tm   = fmaxf(tm, __shfl_down(tm, off));
  }
  __shared__ float red[4][5];
  const int wave = threadIdx.x >> 6, lane = threadIdx.x & 63;
  if (lane == 0) {
    red[wave][0] = cnt; red[wave][1] = sd; red[wave][2] = sd2;
    red[wave][3] = sl2; red[wave][4] = tm;
  }
  __syncthreads();
  if (threadIdx.x == 0) {
    float C = 0, S = 0, S2 = 0, L = 0, T = 0;
#pragma unroll
    for (int w = 0; w < 4; ++w) {
      C += red[w][0]; S += red[w][1]; S2 += red[w][2]; L += red[w][3];
      T = fmaxf(T, red[w][4]);
    }
    atomicAdd(&ws->acc[0], (double)C);
    atomicAdd(&ws->acc[1], (double)S);
    atomicAdd(&ws->acc[2], (double)S2);
    atomicAdd(&ws->acc[3], (double)L);
    atomicMax(&ws->tmax_bits[b], __float_as_uint(T));
  }
}

// ---------------- pass 2: chamfer. Per valid pixel: binary search in sorted bins
// -> min dist^2 (t->b direction) + update per-gap pixel min/max (for b->t).
__global__ __launch_bounds__(256) void k_chamfer(const float* __restrict__ targ,
                                                 const void* __restrict__ mask,
                                                 Ws* __restrict__ ws) {
  const int b = blockIdx.y;
  __shared__ float sbn[NB];
  __shared__ unsigned sgmin[NGAP], sgmax[NGAP];
  const int tid = threadIdx.x;
  if (tid < NB) sbn[tid] = ws->bn[b][tid];
  if (tid < NGAP) { sgmin[tid] = INF_BITS; sgmax[tid] = 0u; }
  const float tmax = __uint_as_float(ws->tmax_bits[b]);
  const int mode = ws->maskmode;
  __syncthreads();

  const int base = b * HW_TOT;
  const int i = (blockIdx.x * 256 + tid) * 4;
  const float4 t4 = *(const float4*)(targ + base + i);
  float t[4] = {t4.x, t4.y, t4.z, t4.w};
  bool v[4];
  if (mode == 0) {
    unsigned mw = *(const unsigned*)((const unsigned char*)mask + base + i);
    v[0] = (mw & 0xFFu) != 0; v[1] = ((mw >> 8) & 0xFFu) != 0;
    v[2] = ((mw >> 16) & 0xFFu) != 0; v[3] = (mw >> 24) != 0;
  } else {
    int4 mi = *(const int4*)((const int*)mask + base + i);
    v[0] = mi.x != 0; v[1] = mi.y != 0; v[2] = mi.z != 0; v[3] = mi.w != 0;
  }

  float csum = 0.f;
#pragma unroll
  for (int k = 0; k < 4; ++k) {
    if (v[k]) {
      float tn = t[k] / tmax;  // faithful f32 division like the reference
      int pos = 0;             // count of bins < tn (reaches max 127 in loop, patched below)
#pragma unroll
      for (int s = 64; s > 0; s >>= 1) {
        int np = pos + s;
        if (np <= NB && sbn[np - 1] < tn) pos = np;
      }
      if (sbn[NB - 1] < tn) pos = NB;
      float c0 = sbn[pos > 0 ? pos - 1 : 0];
      float c1 = sbn[pos < NB ? pos : NB - 1];
      float d0 = tn - c0, d1 = tn - c1;
      csum += fminf(d0 * d0, d1 * d1);
      unsigned tb = __float_as_uint(tn);  // tn >= 0 -> uint order == float order
      atomicMin(&sgmin[pos], tb);
      atomicMax(&sgmax[pos], tb);
    }
  }
#pragma unroll
  for (int off = 32; off > 0; off >>= 1) csum += __shfl_down(csum, off);
  __shared__ float cred[4];
  const int wave = tid >> 6, lane = tid & 63;
  if (lane == 0) cred[wave] = csum;
  __syncthreads();
  if (tid == 0)
    atomicAdd(&ws->t2b[b], (double)(cred[0] + cred[1] + cred[2] + cred[3]));
  if (tid < NGAP && sgmin[tid] != INF_BITS) {
    atomicMin(&ws->gmin[b][tid], sgmin[tid]);
    atomicMax(&ws->gmax[b][tid], sgmax[tid]);
  }
}

// ---------------- finalize: b->t via gap scan, combine with SILog/L2
__global__ __launch_bounds__(512) void k_final(Ws* __restrict__ ws,
                                               float* __restrict__ out) {
  __shared__ float sred[512];
  const int tid = threadIdx.x;
  const int b = tid >> 7, j = tid & 127;
  const float bnj = ws->bn[b][j];
  float md = INFINITY;
  for (int g = 0; g < NGAP; ++g) {
    float gmn = __uint_as_float(ws->gmin[b][g]);
    float gmx = __uint_as_float(ws->gmax[b][g]);
    // distance from bin to the gap's pixel value range; empty gap -> +inf
    float d = fmaxf(fmaxf(gmn - bnj, bnj - gmx), 0.0f);
    md = fminf(md, d * d);
  }
  sred[tid] = isfinite(md) ? md : 0.0f;  // rows with min==inf contribute 0
  __syncthreads();
  for (int s = 64; s > 0; s >>= 1) {
    if (j < s) sred[tid] += sred[tid + s];
    __syncthreads();
  }
  if (tid == 0) {
    double n = ws->acc[0], sd = ws->acc[1], sd2 = ws->acc[2], sl2 = ws->acc[3];
    double mean_d = sd / n, mean_d2 = sd2 / n;
    double silog = 10.0 * sqrt(mean_d2 - 0.85 * mean_d * mean_d);
    double l2 = sqrt(sl2 / n);
    double ch = 0.0;
    for (int bb = 0; bb < NBATCH; ++bb)
      ch += ws->t2b[bb] + (double)sred[bb * 128];
    ch /= (double)NBATCH;
    out[0] = (float)(l2 + silog + ch);
  }
}

extern "C" void kernel_launch(void* const* d_in, const int* in_sizes, int n_in,
                              void* d_out, int out_size, void* d_ws, size_t ws_size,
                              hipStream_t stream) {
  const float* pred = (const float*)d_in[0];
  const float* targ = (const float*)d_in[1];
  const float* bins = (const float*)d_in[2];
  const void*  mask = d_in[3];
  Ws* ws = (Ws*)d_ws;
  float* out = (float*)d_out;

  k_setup<<<dim3(1), dim3(512), 0, stream>>>(bins, mask, ws);
  dim3 grid(HW_TOT / (256 * 4), NBATCH);  // 300 x 4, exact cover (1 float4/thread)
  k_stats<<<grid, dim3(256), 0, stream>>>(pred, targ, mask, ws);
  k_chamfer<<<grid, dim3(256), 0, stream>>>(targ, mask, ws);
  k_final<<<dim3(1), dim3(512), 0, stream>>>(ws, out);
}

// Round 4
// 124.889 us; speedup vs baseline: 1.4502x; 1.4502x over previous
//
#include <hip/hip_runtime.h>
#include <math.h>

#define HW_TOT (480*640)     // 307200 pixels per image
#define NQ (HW_TOT/4)        // 76800 float4-quads per image
#define NBATCH 4
#define NB 128               // bins
#define NGAP (NB+1)          // gaps between sorted bins (below/above included)
#define SBX 75               // stats blocks per batch: 75*256*4 quads == NQ
#define EPSV 1e-10f
#define INF_BITS 0x7F800000u

// ---- helpers ---------------------------------------------------------------
__device__ __forceinline__ int nzbytes(unsigned x) {
  return ((x & 0xFFu) != 0) + ((x & 0xFF00u) != 0) +
         ((x & 0xFF0000u) != 0) + ((x >> 24) != 0);
}

// Per-block mask-dtype sniff: wave 0 samples the first 1024 bytes.
// byte-bool (~973 nonzero) vs float32 (~486) vs int32 (~243); threshold 768.
// Result -> smode (0 = byte mask, 1 = 4-byte word mask, nonzero == true).
__device__ __forceinline__ void sniff_mask(const void* mask, int tid, int* smode) {
  if (tid < 64) {
    const uint4* m16 = (const uint4*)mask;
    uint4 w = m16[tid];
    int c = nzbytes(w.x) + nzbytes(w.y) + nzbytes(w.z) + nzbytes(w.w);
#pragma unroll
    for (int off = 32; off > 0; off >>= 1) c += __shfl_down(c, off);
    if (tid == 0) *smode = (c >= 768) ? 0 : 1;
  }
}

__device__ __forceinline__ void mask4(const void* mask, int e, int mode, bool v[4]) {
  if (mode == 0) {
    unsigned mw = *(const unsigned*)((const unsigned char*)mask + e);
    v[0] = (mw & 0xFFu) != 0;        v[1] = ((mw >> 8) & 0xFFu) != 0;
    v[2] = ((mw >> 16) & 0xFFu) != 0; v[3] = (mw >> 24) != 0;
  } else {
    int4 mi = *(const int4*)((const int*)mask + e);
    v[0] = mi.x != 0; v[1] = mi.y != 0; v[2] = mi.z != 0; v[3] = mi.w != 0;
  }
}

// ---- kernel 1: stats partials (+ fused bin normalize/sort in bx==0 blocks) --
// grid (SBX, NBATCH), 256 threads. NO global atomics: block (bx,b) writes
// pacc[b*SBX+bx] = {cnt, sum_d, sum_d2, sum_l2} and ptmax[b*SBX+bx].
__global__ __launch_bounds__(256) void k_stats(const float* __restrict__ pred,
                                               const float* __restrict__ targ,
                                               const void* __restrict__ mask,
                                               const float* __restrict__ bins,
                                               float* __restrict__ bn,      // [NBATCH][NB] sorted normalized
                                               float4* __restrict__ pacc,   // [NBATCH*SBX]
                                               float* __restrict__ ptmax) { // [NBATCH*SBX]
  const int b = blockIdx.y, bx = blockIdx.x, tid = threadIdx.x;
  __shared__ int smode;
  sniff_mask(mask, tid, &smode);
  __syncthreads();
  const int mode = smode;
  const int base = b * HW_TOT;

  float cnt = 0.f, sd = 0.f, sd2 = 0.f, sl2 = 0.f, tm = 0.f;
#pragma unroll
  for (int k = 0; k < 4; ++k) {
    const int q = bx * 1024 + k * 256 + tid;     // coalesced per iteration
    const int e = base + q * 4;
    const float4 t4 = *(const float4*)(targ + e);
    const float4 p4 = *(const float4*)(pred + e);
    bool v[4];
    mask4(mask, e, mode, v);
    const float t[4] = {t4.x, t4.y, t4.z, t4.w};
    const float p[4] = {p4.x, p4.y, p4.z, p4.w};
#pragma unroll
    for (int j = 0; j < 4; ++j) {
      const float m = v[j] ? 1.f : 0.f;
      const float d = logf(p[j] + EPSV) - logf(t[j] + EPSV);
      cnt += m;
      sd  += m * d;
      sd2 += m * d * d;
      const float er = p[j] - t[j];
      sl2 += m * er * er;
      if (v[j]) tm = fmaxf(tm, t[j]);
    }
  }
#pragma unroll
  for (int off = 32; off > 0; off >>= 1) {
    cnt += __shfl_down(cnt, off);
    sd  += __shfl_down(sd,  off);
    sd2 += __shfl_down(sd2, off);
    sl2 += __shfl_down(sl2, off);
    tm   = fmaxf(tm, __shfl_down(tm, off));
  }
  __shared__ float red[4][5];
  const int wave = tid >> 6, lane = tid & 63;
  if (lane == 0) {
    red[wave][0] = cnt; red[wave][1] = sd; red[wave][2] = sd2;
    red[wave][3] = sl2; red[wave][4] = tm;
  }
  __syncthreads();
  if (tid == 0) {
    float C = 0, S = 0, S2 = 0, L = 0, T = 0;
#pragma unroll
    for (int w = 0; w < 4; ++w) {
      C += red[w][0]; S += red[w][1]; S2 += red[w][2]; L += red[w][3];
      T = fmaxf(T, red[w][4]);
    }
    pacc[b * SBX + bx] = make_float4(C, S, S2, L);
    ptmax[b * SBX + bx] = T;
  }

  // ---- fused setup tail: block bx==0 normalizes + bitonic-sorts batch b bins
  if (bx == 0) {
    __shared__ float sb[NB];
    __shared__ float sred2[64];
    if (tid < NB) sb[tid] = bins[b * NB + tid];
    __syncthreads();
    if (tid < 64) sred2[tid] = fmaxf(sb[tid], sb[tid + 64]);
    __syncthreads();
    for (int s = 32; s > 0; s >>= 1) {
      if (tid < s) sred2[tid] = fmaxf(sred2[tid], sred2[tid + s]);
      __syncthreads();
    }
    const float bmax = sred2[0];
    __syncthreads();
    if (tid < NB) sb[tid] = bins[b * NB + tid] / bmax;  // faithful f32 division
    __syncthreads();
    for (int k = 2; k <= NB; k <<= 1) {
      for (int jj = k >> 1; jj > 0; jj >>= 1) {
        const int ixj = tid ^ jj;
        if (tid < NB && ixj > tid) {
          const float a = sb[tid], c = sb[ixj];
          const bool up = ((tid & k) == 0);
          if (up ? (a > c) : (a < c)) { sb[tid] = c; sb[ixj] = a; }
        }
        __syncthreads();
      }
    }
    if (tid < NB) bn[b * NB + tid] = sb[tid];
  }
}

// ---- kernel 2: chamfer partials. grid (nbx, NBATCH), 256 threads. ----------
// Per valid pixel: binary search in sorted bins -> min dist^2 (t->b), and
// per-gap pixel min/max via LDS atomics; block writes its LDS gap arrays and
// csum to disjoint slots (no global atomics).
__global__ __launch_bounds__(256) void k_chamfer(const float* __restrict__ targ,
                                                 const void* __restrict__ mask,
                                                 const float* __restrict__ bn,
                                                 const float* __restrict__ ptmax,
                                                 float* __restrict__ pcsum,      // [NBATCH*nbx]
                                                 unsigned* __restrict__ pgmin,   // [NBATCH*nbx][NGAP]
                                                 unsigned* __restrict__ pgmax,
                                                 int nbx) {
  const int b = blockIdx.y, bx = blockIdx.x, tid = threadIdx.x;
  __shared__ int smode;
  __shared__ float sbn[NB];
  __shared__ unsigned sgmin[NGAP], sgmax[NGAP];
  __shared__ float stmax;

  sniff_mask(mask, tid, &smode);
  if (tid < NB) sbn[tid] = bn[b * NB + tid];
  if (tid < NGAP) { sgmin[tid] = INF_BITS; sgmax[tid] = 0u; }
  if (tid >= 128 && tid < 192) {               // wave 2: merge SBX tmax partials
    const int l = tid - 128;
    float v = (l < SBX) ? ptmax[b * SBX + l] : 0.f;
    if (l + 64 < SBX) v = fmaxf(v, ptmax[b * SBX + l + 64]);
#pragma unroll
    for (int off = 32; off > 0; off >>= 1) v = fmaxf(v, __shfl_down(v, off));
    if (l == 0) stmax = v;
  }
  __syncthreads();
  const int mode = smode;
  const float tmax = stmax;
  const int base = b * HW_TOT;

  float csum = 0.f;
  for (int q = bx * 256 + tid; q < NQ; q += nbx * 256) {
    const int e = base + q * 4;
    const float4 t4 = *(const float4*)(targ + e);
    bool v[4];
    mask4(mask, e, mode, v);
    const float t[4] = {t4.x, t4.y, t4.z, t4.w};
#pragma unroll
    for (int k = 0; k < 4; ++k) {
      if (v[k]) {
        const float tn = t[k] / tmax;          // faithful f32 division
        int pos = 0;                           // count of bins < tn
#pragma unroll
        for (int s = 64; s > 0; s >>= 1) {
          const int np = pos + s;
          if (np <= NB && sbn[np - 1] < tn) pos = np;
        }
        if (sbn[NB - 1] < tn) pos = NB;
        const float c0 = sbn[pos > 0 ? pos - 1 : 0];
        const float c1 = sbn[pos < NB ? pos : NB - 1];
        const float d0 = tn - c0, d1 = tn - c1;
        csum += fminf(d0 * d0, d1 * d1);
        const unsigned tb = __float_as_uint(tn);  // tn >= 0: uint order == float order
        atomicMin(&sgmin[pos], tb);
        atomicMax(&sgmax[pos], tb);
      }
    }
  }
#pragma unroll
  for (int off = 32; off > 0; off >>= 1) csum += __shfl_down(csum, off);
  __shared__ float cred[4];
  const int wave = tid >> 6, lane = tid & 63;
  if (lane == 0) cred[wave] = csum;
  __syncthreads();
  const int slot = b * nbx + bx;
  if (tid == 0) pcsum[slot] = cred[0] + cred[1] + cred[2] + cred[3];
  if (tid < NGAP) {
    pgmin[slot * NGAP + tid] = sgmin[tid];
    pgmax[slot * NGAP + tid] = sgmax[tid];
  }
}

// ---- kernel 3: final merge + combine. 1 block, 512 threads. ----------------
__global__ __launch_bounds__(512) void k_final(const float* __restrict__ bn,
                                               const float4* __restrict__ pacc,
                                               const float* __restrict__ pcsum,
                                               const unsigned* __restrict__ pgmin,
                                               const unsigned* __restrict__ pgmax,
                                               int nbx,
                                               float* __restrict__ out) {
  const int tid = threadIdx.x;
  __shared__ double wacc[8][4];
  __shared__ unsigned mgmin[NBATCH][NGAP], mgmax[NBATCH][NGAP];
  __shared__ double dcs[NBATCH];
  __shared__ float sred[512];

  // A: merge stats partials (300 float4 -> double4)
  double a0 = 0, a1 = 0, a2 = 0, a3 = 0;
  if (tid < NBATCH * SBX) {
    const float4 p = pacc[tid];
    a0 = p.x; a1 = p.y; a2 = p.z; a3 = p.w;
  }
#pragma unroll
  for (int off = 32; off > 0; off >>= 1) {
    a0 += __shfl_down(a0, off); a1 += __shfl_down(a1, off);
    a2 += __shfl_down(a2, off); a3 += __shfl_down(a3, off);
  }
  if ((tid & 63) == 0) {
    wacc[tid >> 6][0] = a0; wacc[tid >> 6][1] = a1;
    wacc[tid >> 6][2] = a2; wacc[tid >> 6][3] = a3;
  }
  // B: merge per-block gap min/max
  for (int o = tid; o < NBATCH * NGAP; o += 512) {
    const int b = o / NGAP, g = o - b * NGAP;
    unsigned mn = INF_BITS, mx = 0u;
    for (int k = 0; k < nbx; ++k) {
      mn = min(mn, pgmin[(b * nbx + k) * NGAP + g]);
      mx = max(mx, pgmax[(b * nbx + k) * NGAP + g]);
    }
    mgmin[b][g] = mn; mgmax[b][g] = mx;
  }
  // C: merge chamfer csums
  if (tid < NBATCH) {
    double cs = 0.0;
    for (int k = 0; k < nbx; ++k) cs += (double)pcsum[tid * nbx + k];
    dcs[tid] = cs;
  }
  __syncthreads();

  // D: b->t via gap scan (bin never falls strictly inside a gap's pixel range)
  const int b = tid >> 7, j = tid & 127;
  const float bnj = bn[b * NB + j];
  float md = INFINITY;
  for (int g = 0; g < NGAP; ++g) {
    const float gmn = __uint_as_float(mgmin[b][g]);
    const float gmx = __uint_as_float(mgmax[b][g]);
    const float d = fmaxf(fmaxf(gmn - bnj, bnj - gmx), 0.0f);
    md = fminf(md, d * d);
  }
  sred[tid] = isfinite(md) ? md : 0.0f;   // empty-everything rows contribute 0
  __syncthreads();
  for (int s = 64; s > 0; s >>= 1) {
    if (j < s) sred[tid] += sred[tid + s];
    __syncthreads();
  }
  if (tid == 0) {
    double n = 0, sdv = 0, sd2v = 0, sl2v = 0;
#pragma unroll
    for (int w = 0; w < 8; ++w) {
      n += wacc[w][0]; sdv += wacc[w][1]; sd2v += wacc[w][2]; sl2v += wacc[w][3];
    }
    const double mean_d = sdv / n, mean_d2 = sd2v / n;
    const double silog = 10.0 * sqrt(mean_d2 - 0.85 * mean_d * mean_d);
    const double l2 = sqrt(sl2v / n);
    double ch = 0.0;
    for (int bb = 0; bb < NBATCH; ++bb) ch += dcs[bb] + (double)sred[bb * 128];
    ch /= (double)NBATCH;
    out[0] = (float)(l2 + silog + ch);
  }
}

extern "C" void kernel_launch(void* const* d_in, const int* in_sizes, int n_in,
                              void* d_out, int out_size, void* d_ws, size_t ws_size,
                              hipStream_t stream) {
  const float* pred = (const float*)d_in[0];
  const float* targ = (const float*)d_in[1];
  const float* bins = (const float*)d_in[2];
  const void*  mask = d_in[3];
  float* out = (float*)d_out;

  // Workspace layout (offsets fixed; gap-partial size depends on nbx):
  char* w = (char*)d_ws;
  float*  bn    = (float*)w;                    // 2048 B
  float4* pacc  = (float4*)(w + 2048);          // 4800 B -> 6848
  float*  ptmax = (float*)(w + 6848);           // 1200 B -> 8048 (pad to 8064)
  const size_t hdr = 8064;
  auto need = [&](size_t nb) {
    return hdr + 4 * nb * sizeof(float) + 2 * 4 * nb * NGAP * sizeof(unsigned);
  };
  int nbx = 16;                                  // chamfer blocks per batch
  if (ws_size < need(16)) nbx = (ws_size >= need(4)) ? 4 : 1;
  float*    pcsum = (float*)(w + hdr);
  unsigned* pgmin = (unsigned*)(w + hdr + 4 * nbx * sizeof(float));
  unsigned* pgmax = pgmin + 4 * (size_t)nbx * NGAP;

  k_stats<<<dim3(SBX, NBATCH), dim3(256), 0, stream>>>(pred, targ, mask, bins,
                                                       bn, pacc, ptmax);
  k_chamfer<<<dim3(nbx, NBATCH), dim3(256), 0, stream>>>(targ, mask, bn, ptmax,
                                                         pcsum, pgmin, pgmax, nbx);
  k_final<<<dim3(1), dim3(512), 0, stream>>>(bn, pacc, pcsum, pgmin, pgmax, nbx, out);
}